// Round 2
// baseline (567.962 us; speedup 1.0000x reference)
//
#include <hip/hip_runtime.h>
#include <math.h>

#define Bg   128
#define Ng   256
#define Dg   256
#define Hg   8
#define HDg  32
#define Eg   524288
#define Kg   128
#define BNg  32768
#define SENT 16384   // = Bg*Kg

// ---------------- K1: fused QKV projection, 128x128 tile, 8x8/thread ----------
__global__ __launch_bounds__(256) void qkv_gemm(
    const float* __restrict__ x,
    const float* __restrict__ Wq, const float* __restrict__ bq,
    const float* __restrict__ Wk, const float* __restrict__ bk,
    const float* __restrict__ Wv, const float* __restrict__ bv,
    float* __restrict__ Qo, float* __restrict__ Ko, float* __restrict__ Vo)
{
    const float* W; const float* bias; float* out;
    if (blockIdx.z == 0)      { W = Wq; bias = bq; out = Qo; }
    else if (blockIdx.z == 1) { W = Wk; bias = bk; out = Ko; }
    else                      { W = Wv; bias = bv; out = Vo; }
    __shared__ float As[16][136];  // [k][m], padded
    __shared__ float Bs[16][132];  // [k][n], padded
    const int tid = threadIdx.x;
    const int tx = tid & 15, ty = tid >> 4;
    const int m0 = blockIdx.x * 128;
    const int n0 = blockIdx.y * 128;
    float acc[8][8] = {};
    const int ar = tid >> 1, ak = (tid & 1) * 8;     // A staging coords
    const int bk_ = tid >> 4, bn = (tid & 15) * 8;   // B staging coords
    for (int k0 = 0; k0 < Dg; k0 += 16) {
        float4 a0 = *reinterpret_cast<const float4*>(x + (size_t)(m0 + ar) * Dg + k0 + ak);
        float4 a1 = *reinterpret_cast<const float4*>(x + (size_t)(m0 + ar) * Dg + k0 + ak + 4);
        float4 b0 = *reinterpret_cast<const float4*>(W + (size_t)(k0 + bk_) * Dg + n0 + bn);
        float4 b1 = *reinterpret_cast<const float4*>(W + (size_t)(k0 + bk_) * Dg + n0 + bn + 4);
        As[ak+0][ar] = a0.x; As[ak+1][ar] = a0.y; As[ak+2][ar] = a0.z; As[ak+3][ar] = a0.w;
        As[ak+4][ar] = a1.x; As[ak+5][ar] = a1.y; As[ak+6][ar] = a1.z; As[ak+7][ar] = a1.w;
        *reinterpret_cast<float4*>(&Bs[bk_][bn])   = b0;
        *reinterpret_cast<float4*>(&Bs[bk_][bn+4]) = b1;
        __syncthreads();
        #pragma unroll
        for (int kk = 0; kk < 16; ++kk) {
            float av[8], bw[8];
            *reinterpret_cast<float4*>(&av[0]) = *reinterpret_cast<const float4*>(&As[kk][ty*8]);
            *reinterpret_cast<float4*>(&av[4]) = *reinterpret_cast<const float4*>(&As[kk][ty*8+4]);
            *reinterpret_cast<float4*>(&bw[0]) = *reinterpret_cast<const float4*>(&Bs[kk][tx*8]);
            *reinterpret_cast<float4*>(&bw[4]) = *reinterpret_cast<const float4*>(&Bs[kk][tx*8+4]);
            #pragma unroll
            for (int i = 0; i < 8; ++i)
                #pragma unroll
                for (int j = 0; j < 8; ++j)
                    acc[i][j] = fmaf(av[i], bw[j], acc[i][j]);
        }
        __syncthreads();
    }
    #pragma unroll
    for (int i = 0; i < 8; ++i) {
        int m = m0 + ty*8 + i;
        int b = m >> 8, n_ = m & 255;
        #pragma unroll
        for (int jq = 0; jq < 2; ++jq) {
            int c0 = n0 + tx*8 + jq*4;
            int h = c0 >> 5, hd = c0 & 31;
            float4 v;
            v.x = acc[i][jq*4+0] + bias[c0+0];
            v.y = acc[i][jq*4+1] + bias[c0+1];
            v.z = acc[i][jq*4+2] + bias[c0+2];
            v.w = acc[i][jq*4+3] + bias[c0+3];
            *reinterpret_cast<float4*>(out + ((size_t)(b*Hg + h) * Ng + n_) * HDg + hd) = v;
        }
    }
}

// ---------------- K2: attention, key-tiled deferred-rescale softmax ----------
__global__ __launch_bounds__(256) void attn_kernel(
    const float* Q, const float* __restrict__ Kx, const float* __restrict__ Vx,
    const float* __restrict__ dist, float* AO)
{
    __shared__ float ks[Ng][HDg];
    __shared__ float vs[Ng][HDg];
    const int bh = blockIdx.x;
    const int b  = bh >> 3;
    const int tid = threadIdx.x;
    const float* kb = Kx + (size_t)bh * Ng * HDg;
    const float* vb = Vx + (size_t)bh * Ng * HDg;
    float* ksf = &ks[0][0];
    float* vsf = &vs[0][0];
    for (int i = tid * 4; i < Ng * HDg; i += 1024) {
        *reinterpret_cast<float4*>(ksf + i) = *reinterpret_cast<const float4*>(kb + i);
        *reinterpret_cast<float4*>(vsf + i) = *reinterpret_cast<const float4*>(vb + i);
    }
    float q[HDg];
    const float* qrow = Q + ((size_t)bh * Ng + tid) * HDg;
    #pragma unroll
    for (int d = 0; d < HDg; d += 4) {
        float4 t4 = *reinterpret_cast<const float4*>(qrow + d);
        q[d]   = t4.x * 0.17677669529663687f;   // 1/sqrt(32) folded into q
        q[d+1] = t4.y * 0.17677669529663687f;
        q[d+2] = t4.z * 0.17677669529663687f;
        q[d+3] = t4.w * 0.17677669529663687f;
    }
    __syncthreads();
    const float* drow = dist + (size_t)b * Ng * Ng + (size_t)tid * Ng;
    float m = -1e30f, l = 0.f;
    float o[HDg] = {};
    for (int j0 = 0; j0 < Ng; j0 += 16) {
        float s[16];
        #pragma unroll
        for (int jj = 0; jj < 16; jj += 4) {
            float4 dd = *reinterpret_cast<const float4*>(drow + j0 + jj);
            s[jj] = dd.x; s[jj+1] = dd.y; s[jj+2] = dd.z; s[jj+3] = dd.w;
        }
        #pragma unroll
        for (int jj = 0; jj < 16; ++jj) {
            const float* kr = &ks[j0+jj][0];
            float acc = s[jj];
            #pragma unroll
            for (int d = 0; d < HDg; ++d) acc = fmaf(q[d], kr[d], acc);
            s[jj] = acc;
        }
        float tm = s[0];
        #pragma unroll
        for (int jj = 1; jj < 16; ++jj) tm = fmaxf(tm, s[jj]);
        float nm = fmaxf(m, tm);
        float corr = __expf(m - nm);    // first tile: exp(-huge)=0
        l *= corr;
        #pragma unroll
        for (int d = 0; d < HDg; ++d) o[d] *= corr;
        m = nm;
        #pragma unroll
        for (int jj = 0; jj < 16; ++jj) {
            float p = __expf(s[jj] - m);
            l += p;
            const float* vr = &vs[j0+jj][0];
            #pragma unroll
            for (int d = 0; d < HDg; ++d) o[d] = fmaf(p, vr[d], o[d]);
        }
    }
    float inv = 1.f / l;
    float* orow = AO + ((size_t)bh * Ng + tid) * HDg;
    #pragma unroll
    for (int d = 0; d < HDg; d += 4) {
        float4 t4;
        t4.x = o[d]*inv; t4.y = o[d+1]*inv; t4.z = o[d+2]*inv; t4.w = o[d+3]*inv;
        *reinterpret_cast<float4*>(orow + d) = t4;
    }
}

// ---------------- K3: output projection, 128x128 tile, A from [b,h,n,hd] -----
__global__ __launch_bounds__(256) void out_gemm(
    const float* __restrict__ AO, const float* __restrict__ Wo,
    const float* __restrict__ bo, float* __restrict__ enc)
{
    __shared__ float As[16][136];
    __shared__ float Bs[16][132];
    const int tid = threadIdx.x;
    const int tx = tid & 15, ty = tid >> 4;
    const int m0 = blockIdx.x * 128;
    const int n0 = blockIdx.y * 128;
    float acc[8][8] = {};
    const int ar = tid >> 1, ak = (tid & 1) * 8;
    const int bk_ = tid >> 4, bn = (tid & 15) * 8;
    const int am = m0 + ar;
    const int ab = am >> 8, an = am & 255;
    for (int k0 = 0; k0 < Dg; k0 += 16) {
        int kk0 = k0 + ak;
        int h = kk0 >> 5, hd = kk0 & 31;
        const float* asrc = AO + ((size_t)(ab*Hg + h) * Ng + an) * HDg + hd;
        float4 a0 = *reinterpret_cast<const float4*>(asrc);
        float4 a1 = *reinterpret_cast<const float4*>(asrc + 4);
        float4 b0 = *reinterpret_cast<const float4*>(Wo + (size_t)(k0 + bk_) * Dg + n0 + bn);
        float4 b1 = *reinterpret_cast<const float4*>(Wo + (size_t)(k0 + bk_) * Dg + n0 + bn + 4);
        As[ak+0][ar] = a0.x; As[ak+1][ar] = a0.y; As[ak+2][ar] = a0.z; As[ak+3][ar] = a0.w;
        As[ak+4][ar] = a1.x; As[ak+5][ar] = a1.y; As[ak+6][ar] = a1.z; As[ak+7][ar] = a1.w;
        *reinterpret_cast<float4*>(&Bs[bk_][bn])   = b0;
        *reinterpret_cast<float4*>(&Bs[bk_][bn+4]) = b1;
        __syncthreads();
        #pragma unroll
        for (int kk = 0; kk < 16; ++kk) {
            float av[8], bw[8];
            *reinterpret_cast<float4*>(&av[0]) = *reinterpret_cast<const float4*>(&As[kk][ty*8]);
            *reinterpret_cast<float4*>(&av[4]) = *reinterpret_cast<const float4*>(&As[kk][ty*8+4]);
            *reinterpret_cast<float4*>(&bw[0]) = *reinterpret_cast<const float4*>(&Bs[kk][tx*8]);
            *reinterpret_cast<float4*>(&bw[4]) = *reinterpret_cast<const float4*>(&Bs[kk][tx*8+4]);
            #pragma unroll
            for (int i = 0; i < 8; ++i)
                #pragma unroll
                for (int j = 0; j < 8; ++j)
                    acc[i][j] = fmaf(av[i], bw[j], acc[i][j]);
        }
        __syncthreads();
    }
    #pragma unroll
    for (int i = 0; i < 8; ++i) {
        int m = m0 + ty*8 + i;
        #pragma unroll
        for (int jq = 0; jq < 2; ++jq) {
            int c0 = n0 + tx*8 + jq*4;
            float4 v;
            v.x = acc[i][jq*4+0] + bo[c0+0];
            v.y = acc[i][jq*4+1] + bo[c0+1];
            v.z = acc[i][jq*4+2] + bo[c0+2];
            v.w = acc[i][jq*4+3] + bo[c0+3];
            *reinterpret_cast<float4*>(enc + (size_t)m * Dg + c0) = v;
        }
    }
}

// ---------------- K4: pooling scores (raw, un-normalized) ----------------
__global__ __launch_bounds__(256) void score_kernel(
    const float* __restrict__ enc, const float* __restrict__ pw, float* __restrict__ score)
{
    int row  = blockIdx.x * 8 + (threadIdx.x >> 5);
    int lane = threadIdx.x & 31;
    const float* r = enc + (size_t)row * Dg;
    float s = 0.f;
    for (int d = lane; d < Dg; d += 32) s = fmaf(r[d], pw[d], s);
    #pragma unroll
    for (int off = 16; off > 0; off >>= 1) s += __shfl_xor(s, off);
    if (lane == 0) score[row] = s;
}

__global__ void norm_kernel(const float* __restrict__ pw, float* __restrict__ inv_norm)
{
    int t = threadIdx.x;
    float s = 0.f;
    for (int d = t; d < Dg; d += 64) s = fmaf(pw[d], pw[d], s);
    #pragma unroll
    for (int off = 32; off > 0; off >>= 1) s += __shfl_xor(s, off);
    if (t == 0) *inv_norm = 1.0f / sqrtf(s);
}

// ---------------- K5: per-graph exact top-K via rank count ----------------
__global__ __launch_bounds__(256) void topk_kernel(
    const float* __restrict__ score, float* __restrict__ vals, int* __restrict__ idxs,
    int* __restrict__ new_id, float* __restrict__ out_batch)
{
    __shared__ float sh[Ng];
    int bgr = blockIdx.x, t = threadIdx.x;
    float mine = score[(size_t)bgr * Ng + t];
    sh[t] = mine;
    __syncthreads();
    int cnt = 0;
    for (int j = 0; j < Ng; ++j) {
        float v = sh[j];
        cnt += (v > mine || (v == mine && j < t)) ? 1 : 0;
    }
    if (cnt < Kg) {
        int pos = bgr * Kg + cnt;
        vals[pos] = mine;
        idxs[pos] = t;
        new_id[bgr * Ng + t] = pos;
        out_batch[pos] = (float)bgr;
    } else {
        new_id[bgr * Ng + t] = SENT;
    }
}

// ---------------- K6: gather + tanh scale ----------------
__global__ __launch_bounds__(256) void subx_kernel(
    const float* __restrict__ enc, const float* __restrict__ vals,
    const int* __restrict__ idxs, const float* __restrict__ inv_norm,
    float* __restrict__ out_subx)
{
    int j    = blockIdx.x * 4 + (threadIdx.x >> 6);
    int lane = threadIdx.x & 63;
    int bgr  = j >> 7;
    int src  = bgr * Ng + idxs[j];
    float scale = tanhf(vals[j] * (*inv_norm));
    float4 v = reinterpret_cast<const float4*>(enc + (size_t)src * Dg)[lane];
    v.x *= scale; v.y *= scale; v.z *= scale; v.w *= scale;
    reinterpret_cast<float4*>(out_subx + (size_t)j * Dg)[lane] = v;
}

// ---------------- edge pipeline ----------------
__global__ __launch_bounds__(256) void edge_hist(
    const int* __restrict__ ei, const int* __restrict__ new_id, int* __restrict__ counts)
{
    int e = blockIdx.x * 256 + threadIdx.x;
    int r = new_id[ei[e]];
    int c = new_id[ei[Eg + e]];
    if (r != SENT && c != SENT) atomicAdd(&counts[r], 1);
}

__global__ __launch_bounds__(256) void scan_kernel(
    const int* __restrict__ counts, int* __restrict__ offsets)
{
    __shared__ int tmp[256];
    __shared__ int carry_s;
    int t = threadIdx.x;
    if (t == 0) carry_s = 0;
    __syncthreads();
    for (int base = 0; base < SENT; base += 256) {
        int v = counts[base + t];
        tmp[t] = v;
        __syncthreads();
        for (int off = 1; off < 256; off <<= 1) {
            int add = (t >= off) ? tmp[t - off] : 0;
            __syncthreads();
            tmp[t] += add;
            __syncthreads();
        }
        int incl  = tmp[t];
        int carry = carry_s;
        offsets[base + t] = carry + incl - v;   // exclusive
        __syncthreads();
        if (t == 255) carry_s = carry + incl;
        __syncthreads();
    }
    if (t == 0) offsets[SENT] = carry_s;
}

__global__ __launch_bounds__(256) void edge_scatter(
    const int* __restrict__ ei, const int* __restrict__ new_id,
    const int* __restrict__ offsets, int* __restrict__ cursor, int* __restrict__ bucket)
{
    int e = blockIdx.x * 256 + threadIdx.x;
    int r = new_id[ei[e]];
    int c = new_id[ei[Eg + e]];
    if (r != SENT && c != SENT) {
        int pos = offsets[r] + atomicAdd(&cursor[r], 1);
        bucket[pos] = c;
    }
}

__global__ __launch_bounds__(256) void edge_sort_emit(
    const int* __restrict__ offsets, int* bucket, float* __restrict__ out_edges)
{
    int r = blockIdx.x * 256 + threadIdx.x;   // 0..16383
    int s = offsets[r], e = offsets[r + 1];
    for (int i = s + 1; i < e; ++i) {          // insertion sort (avg ~8 elems)
        int key = bucket[i];
        int j = i - 1;
        while (j >= s && bucket[j] > key) { bucket[j+1] = bucket[j]; --j; }
        bucket[j+1] = key;
    }
    float rf = (float)r;
    for (int i = s; i < e; ++i) {
        out_edges[i]      = rf;
        out_edges[Eg + i] = (float)bucket[i];
    }
}

__global__ __launch_bounds__(256) void edge_fill(
    const int* __restrict__ offsets, float* __restrict__ out_edges)
{
    int p = blockIdx.x * 256 + threadIdx.x;
    if (p >= offsets[SENT]) {
        out_edges[p]      = (float)SENT;
        out_edges[Eg + p] = (float)SENT;
    }
}

// ---------------- launch ----------------
extern "C" void kernel_launch(void* const* d_in, const int* in_sizes, int n_in,
                              void* d_out, int out_size, void* d_ws, size_t ws_size,
                              hipStream_t stream)
{
    const float* x    = (const float*)d_in[0];
    const float* dist = (const float*)d_in[2];
    const int*   ei   = (const int*)d_in[3];
    const float* Wq = (const float*)d_in[5];
    const float* bq = (const float*)d_in[6];
    const float* Wk = (const float*)d_in[7];
    const float* bk = (const float*)d_in[8];
    const float* Wv = (const float*)d_in[9];
    const float* bv = (const float*)d_in[10];
    const float* Wo = (const float*)d_in[11];
    const float* bo = (const float*)d_in[12];
    const float* pw = (const float*)d_in[13];

    float* out       = (float*)d_out;
    float* enc_out   = out;                     // [B*N*D]        8,388,608
    float* subx_out  = out + 8388608;           // [B*K*D]        4,194,304
    float* edge_out  = out + 12582912;          // [2*E]          1,048,576
    float* batch_out = out + 13631488;          // [B*K]             16,384

    float* ws     = (float*)d_ws;
    float* Q      = ws;                         // 8,388,608 (reused as attn out)
    float* Kx     = ws + 8388608;
    float* Vx     = ws + 16777216;
    float* score  = ws + 25165824;              // 32768
    float* vals   = ws + 25198592;              // 16384
    int*   idxs   = (int*)(ws + 25214976);      // 16384
    int*   new_id = (int*)(ws + 25231360);      // 32768
    int*   counts = (int*)(ws + 25264128);      // 16384
    int*   offsets= (int*)(ws + 25280512);      // 16385 (pad to 16416)
    int*   cursor = (int*)(ws + 25296928);      // 16384
    float* inv_nm = ws + 25313312;              // 1 (pad 32)
    int*   bucket = (int*)(ws + 25313344);      // 524288

    hipMemsetAsync(counts, 0, SENT * sizeof(int), stream);
    hipMemsetAsync(cursor, 0, SENT * sizeof(int), stream);

    qkv_gemm      <<<dim3(BNg/128, Dg/128, 3), 256, 0, stream>>>(x, Wq,bq, Wk,bk, Wv,bv, Q, Kx, Vx);
    attn_kernel   <<<dim3(Bg*Hg),              256, 0, stream>>>(Q, Kx, Vx, dist, Q);
    out_gemm      <<<dim3(BNg/128, Dg/128),    256, 0, stream>>>(Q, Wo, bo, enc_out);
    score_kernel  <<<dim3(BNg/8),              256, 0, stream>>>(enc_out, pw, score);
    norm_kernel   <<<dim3(1),                   64, 0, stream>>>(pw, inv_nm);
    topk_kernel   <<<dim3(Bg),                 256, 0, stream>>>(score, vals, idxs, new_id, batch_out);
    subx_kernel   <<<dim3((Bg*Kg)/4),          256, 0, stream>>>(enc_out, vals, idxs, inv_nm, subx_out);
    edge_hist     <<<dim3(Eg/256),             256, 0, stream>>>(ei, new_id, counts);
    scan_kernel   <<<dim3(1),                  256, 0, stream>>>(counts, offsets);
    edge_scatter  <<<dim3(Eg/256),             256, 0, stream>>>(ei, new_id, offsets, cursor, bucket);
    edge_sort_emit<<<dim3(SENT/256),           256, 0, stream>>>(offsets, bucket, edge_out);
    edge_fill     <<<dim3(Eg/256),             256, 0, stream>>>(offsets, edge_out);
    (void)in_sizes; (void)n_in; (void)out_size; (void)ws_size;
}

// Round 3
// 418.717 us; speedup vs baseline: 1.3564x; 1.3564x over previous
//
#include <hip/hip_runtime.h>
#include <math.h>

#define Bg   128
#define Ng   256
#define Dg   256
#define Hg   8
#define HDg  32
#define Eg   524288
#define Kg   128
#define BNg  32768
#define SENT 16384   // = Bg*Kg

using bf16x8 = __attribute__((ext_vector_type(8))) short;
using f32x4  = __attribute__((ext_vector_type(4))) float;

// split f32 -> bf16 hi (truncated) + bf16 lo (residual), error ~2^-16 rel
__device__ inline void split2(float x, short &h, short &l) {
    unsigned u = __float_as_uint(x);
    h = (short)(u >> 16);
    float hf = __uint_as_float(u & 0xffff0000u);
    float r = x - hf;
    l = (short)(__float_as_uint(r) >> 16);
}
// pack: low 16 = hi bf16, high 16 = lo bf16
__device__ inline unsigned packsplit(float x) {
    unsigned u = __float_as_uint(x);
    float hf = __uint_as_float(u & 0xffff0000u);
    float r = x - hf;
    unsigned lu = __float_as_uint(r);
    return (u >> 16) | (lu & 0xffff0000u);
}

// ---------------- K1: fused QKV projection, 128x128 tile, 8x8/thread ----------
__global__ __launch_bounds__(256) void qkv_gemm(
    const float* __restrict__ x,
    const float* __restrict__ Wq, const float* __restrict__ bq,
    const float* __restrict__ Wk, const float* __restrict__ bk,
    const float* __restrict__ Wv, const float* __restrict__ bv,
    float* __restrict__ Qo, float* __restrict__ Ko, float* __restrict__ Vo)
{
    const float* W; const float* bias; float* out;
    if (blockIdx.z == 0)      { W = Wq; bias = bq; out = Qo; }
    else if (blockIdx.z == 1) { W = Wk; bias = bk; out = Ko; }
    else                      { W = Wv; bias = bv; out = Vo; }
    __shared__ float As[16][136];
    __shared__ float Bs[16][132];
    const int tid = threadIdx.x;
    const int tx = tid & 15, ty = tid >> 4;
    const int m0 = blockIdx.x * 128;
    const int n0 = blockIdx.y * 128;
    float acc[8][8] = {};
    const int ar = tid >> 1, ak = (tid & 1) * 8;
    const int bk_ = tid >> 4, bn = (tid & 15) * 8;
    for (int k0 = 0; k0 < Dg; k0 += 16) {
        float4 a0 = *reinterpret_cast<const float4*>(x + (size_t)(m0 + ar) * Dg + k0 + ak);
        float4 a1 = *reinterpret_cast<const float4*>(x + (size_t)(m0 + ar) * Dg + k0 + ak + 4);
        float4 b0 = *reinterpret_cast<const float4*>(W + (size_t)(k0 + bk_) * Dg + n0 + bn);
        float4 b1 = *reinterpret_cast<const float4*>(W + (size_t)(k0 + bk_) * Dg + n0 + bn + 4);
        As[ak+0][ar] = a0.x; As[ak+1][ar] = a0.y; As[ak+2][ar] = a0.z; As[ak+3][ar] = a0.w;
        As[ak+4][ar] = a1.x; As[ak+5][ar] = a1.y; As[ak+6][ar] = a1.z; As[ak+7][ar] = a1.w;
        *reinterpret_cast<float4*>(&Bs[bk_][bn])   = b0;
        *reinterpret_cast<float4*>(&Bs[bk_][bn+4]) = b1;
        __syncthreads();
        #pragma unroll
        for (int kk = 0; kk < 16; ++kk) {
            float av[8], bw[8];
            *reinterpret_cast<float4*>(&av[0]) = *reinterpret_cast<const float4*>(&As[kk][ty*8]);
            *reinterpret_cast<float4*>(&av[4]) = *reinterpret_cast<const float4*>(&As[kk][ty*8+4]);
            *reinterpret_cast<float4*>(&bw[0]) = *reinterpret_cast<const float4*>(&Bs[kk][tx*8]);
            *reinterpret_cast<float4*>(&bw[4]) = *reinterpret_cast<const float4*>(&Bs[kk][tx*8+4]);
            #pragma unroll
            for (int i = 0; i < 8; ++i)
                #pragma unroll
                for (int j = 0; j < 8; ++j)
                    acc[i][j] = fmaf(av[i], bw[j], acc[i][j]);
        }
        __syncthreads();
    }
    #pragma unroll
    for (int i = 0; i < 8; ++i) {
        int m = m0 + ty*8 + i;
        int b = m >> 8, n_ = m & 255;
        #pragma unroll
        for (int jq = 0; jq < 2; ++jq) {
            int c0 = n0 + tx*8 + jq*4;
            int h = c0 >> 5, hd = c0 & 31;
            float4 v;
            v.x = acc[i][jq*4+0] + bias[c0+0];
            v.y = acc[i][jq*4+1] + bias[c0+1];
            v.z = acc[i][jq*4+2] + bias[c0+2];
            v.w = acc[i][jq*4+3] + bias[c0+3];
            *reinterpret_cast<float4*>(out + ((size_t)(b*Hg + h) * Ng + n_) * HDg + hd) = v;
        }
    }
}

// ---------------- K2: MFMA flash attention --------------------------------
// 1 block per (b,h); 4 waves x 64 q-rows; key chunks of 32; 16x16x32 bf16 MFMA
// with 3-term hi/lo split (~f32 accuracy). Static softmax offset 16 (scores
// statistically bounded |s|<~9 -> exp(s-16) in [e^-24, e^-8], no overflow).
__global__ __launch_bounds__(256) void attn_mfma(
    const float* Qf, const float* __restrict__ Kx,
    const float* __restrict__ Vx, const float* __restrict__ dist,
    float* AO)
{
    __shared__ short    Khi[2][32][40];     // [buf][key][hd] pitch 40
    __shared__ short    Klo[2][32][40];
    __shared__ unsigned Vt [2][32][36];     // [buf][d][key] packed (lo<<16|hi), pitch 36
    __shared__ unsigned P32[4][64][36];     // [wave][q][key] packed, pitch 36

    const int bh = blockIdx.x;
    const int b  = bh >> 3;
    const int tid = threadIdx.x;
    const int w = tid >> 6;
    const int lane = tid & 63;
    const int g = lane >> 4;
    const int li = lane & 15;
    const int q0 = w * 64;

    // Q fragments, scaled by 1/sqrt(32), split hi/lo
    bf16x8 qh[4], ql[4];
    #pragma unroll
    for (int tq = 0; tq < 4; ++tq) {
        const float* qp = Qf + ((size_t)bh * Ng + q0 + tq*16 + li) * HDg + g*8;
        float4 qa = *(const float4*)qp;
        float4 qb = *(const float4*)(qp + 4);
        float v[8] = {qa.x,qa.y,qa.z,qa.w,qb.x,qb.y,qb.z,qb.w};
        #pragma unroll
        for (int j = 0; j < 8; ++j) {
            short h,l; split2(v[j] * 0.17677669529663687f, h, l);
            qh[tq][j] = h; ql[tq][j] = l;
        }
    }

    // stage chunk 0 into buf 0
    {
        int key = tid >> 3, e0 = (tid & 7) * 4;
        float4 kv = *(const float4*)(Kx + ((size_t)bh*Ng + key) * HDg + e0);
        float4 vv = *(const float4*)(Vx + ((size_t)bh*Ng + key) * HDg + e0);
        float ka[4] = {kv.x,kv.y,kv.z,kv.w}, va[4] = {vv.x,vv.y,vv.z,vv.w};
        #pragma unroll
        for (int i = 0; i < 4; ++i) {
            short h,l; split2(ka[i], h, l);
            Khi[0][key][e0+i] = h; Klo[0][key][e0+i] = l;
            Vt[0][e0+i][key] = packsplit(va[i]);
        }
    }
    __syncthreads();

    f32x4 O[4][2];
    #pragma unroll
    for (int tq=0;tq<4;++tq)
        #pragma unroll
        for (int td=0;td<2;++td) O[tq][td] = (f32x4){0.f,0.f,0.f,0.f};
    float lpart[4][4] = {};

    for (int ch = 0; ch < 8; ++ch) {
        const int cur = ch & 1;
        // stage next chunk into alternate buffer (overlaps with compute)
        if (ch < 7) {
            int key = tid >> 3, e0 = (tid & 7) * 4;
            float4 kv = *(const float4*)(Kx + ((size_t)bh*Ng + (ch+1)*32 + key) * HDg + e0);
            float4 vv = *(const float4*)(Vx + ((size_t)bh*Ng + (ch+1)*32 + key) * HDg + e0);
            float ka[4]={kv.x,kv.y,kv.z,kv.w}, va[4]={vv.x,vv.y,vv.z,vv.w};
            int nb = cur ^ 1;
            #pragma unroll
            for (int i = 0; i < 4; ++i) {
                short h,l; split2(ka[i], h, l);
                Khi[nb][key][e0+i] = h; Klo[nb][key][e0+i] = l;
                Vt[nb][e0+i][key] = packsplit(va[i]);
            }
        }
        // S = Q.K^T (scaled) + dist; dist loads seed the accumulators
        f32x4 sacc[4][2];
        const float* dbase = dist + (size_t)b*Ng*Ng + ch*32;
        #pragma unroll
        for (int tq = 0; tq < 4; ++tq)
            #pragma unroll
            for (int tc = 0; tc < 2; ++tc) {
                const float* dp = dbase + (size_t)(q0 + tq*16 + g*4)*Ng + tc*16 + li;
                f32x4 s;
                s[0]=dp[0]; s[1]=dp[Ng]; s[2]=dp[2*Ng]; s[3]=dp[3*Ng];
                sacc[tq][tc] = s;
            }
        bf16x8 kbh[2], kbl[2];
        #pragma unroll
        for (int tc = 0; tc < 2; ++tc) {
            kbh[tc] = *(const bf16x8*)&Khi[cur][tc*16+li][g*8];
            kbl[tc] = *(const bf16x8*)&Klo[cur][tc*16+li][g*8];
        }
        #pragma unroll
        for (int tq = 0; tq < 4; ++tq)
            #pragma unroll
            for (int tc = 0; tc < 2; ++tc) {
                sacc[tq][tc] = __builtin_amdgcn_mfma_f32_16x16x32_bf16(qh[tq], kbh[tc], sacc[tq][tc], 0,0,0);
                sacc[tq][tc] = __builtin_amdgcn_mfma_f32_16x16x32_bf16(qh[tq], kbl[tc], sacc[tq][tc], 0,0,0);
                sacc[tq][tc] = __builtin_amdgcn_mfma_f32_16x16x32_bf16(ql[tq], kbh[tc], sacc[tq][tc], 0,0,0);
            }
        // softmax with static offset; accumulate row partial sums; write P
        #pragma unroll
        for (int tq = 0; tq < 4; ++tq)
            #pragma unroll
            for (int tc = 0; tc < 2; ++tc)
                #pragma unroll
                for (int r = 0; r < 4; ++r) {
                    float p = __expf(sacc[tq][tc][r] - 16.f);
                    lpart[tq][r] += p;
                    P32[w][tq*16 + g*4 + r][tc*16 + li] = packsplit(p);
                }
        __syncthreads();   // P visible (and staging writes drained)
        // PV: O += P.V  (3-term split)
        bf16x8 vbh[2], vbl[2];
        #pragma unroll
        for (int td = 0; td < 2; ++td) {
            unsigned tmp[8];
            *(uint4*)&tmp[0] = *(const uint4*)&Vt[cur][td*16+li][g*8];
            *(uint4*)&tmp[4] = *(const uint4*)&Vt[cur][td*16+li][g*8+4];
            #pragma unroll
            for (int j=0;j<8;++j){ vbh[td][j]=(short)(tmp[j]&0xffff); vbl[td][j]=(short)(tmp[j]>>16); }
        }
        #pragma unroll
        for (int tq = 0; tq < 4; ++tq) {
            unsigned tmp[8];
            *(uint4*)&tmp[0] = *(const uint4*)&P32[w][tq*16+li][g*8];
            *(uint4*)&tmp[4] = *(const uint4*)&P32[w][tq*16+li][g*8+4];
            bf16x8 ph, pl;
            #pragma unroll
            for (int j=0;j<8;++j){ ph[j]=(short)(tmp[j]&0xffff); pl[j]=(short)(tmp[j]>>16); }
            #pragma unroll
            for (int td = 0; td < 2; ++td) {
                O[tq][td] = __builtin_amdgcn_mfma_f32_16x16x32_bf16(ph, vbh[td], O[tq][td], 0,0,0);
                O[tq][td] = __builtin_amdgcn_mfma_f32_16x16x32_bf16(ph, vbl[td], O[tq][td], 0,0,0);
                O[tq][td] = __builtin_amdgcn_mfma_f32_16x16x32_bf16(pl, vbh[td], O[tq][td], 0,0,0);
            }
        }
        __syncthreads();   // buffers free for next stage
    }
    // epilogue: finish row sums (butterfly over the 16-lane group), normalize, store
    #pragma unroll
    for (int tq = 0; tq < 4; ++tq)
        #pragma unroll
        for (int r = 0; r < 4; ++r) {
            float s = lpart[tq][r];
            s += __shfl_xor(s, 1); s += __shfl_xor(s, 2);
            s += __shfl_xor(s, 4); s += __shfl_xor(s, 8);
            lpart[tq][r] = 1.f / s;
        }
    #pragma unroll
    for (int tq = 0; tq < 4; ++tq)
        #pragma unroll
        for (int td = 0; td < 2; ++td)
            #pragma unroll
            for (int r = 0; r < 4; ++r) {
                int q = q0 + tq*16 + g*4 + r;
                AO[((size_t)bh*Ng + q)*HDg + td*16 + li] = O[tq][td][r] * lpart[tq][r];
            }
}

// ---------------- K3: output projection, 128x128 tile, A from [b,h,n,hd] -----
__global__ __launch_bounds__(256) void out_gemm(
    const float* __restrict__ AO, const float* __restrict__ Wo,
    const float* __restrict__ bo, float* __restrict__ enc)
{
    __shared__ float As[16][136];
    __shared__ float Bs[16][132];
    const int tid = threadIdx.x;
    const int tx = tid & 15, ty = tid >> 4;
    const int m0 = blockIdx.x * 128;
    const int n0 = blockIdx.y * 128;
    float acc[8][8] = {};
    const int ar = tid >> 1, ak = (tid & 1) * 8;
    const int bk_ = tid >> 4, bn = (tid & 15) * 8;
    const int am = m0 + ar;
    const int ab = am >> 8, an = am & 255;
    for (int k0 = 0; k0 < Dg; k0 += 16) {
        int kk0 = k0 + ak;
        int h = kk0 >> 5, hd = kk0 & 31;
        const float* asrc = AO + ((size_t)(ab*Hg + h) * Ng + an) * HDg + hd;
        float4 a0 = *reinterpret_cast<const float4*>(asrc);
        float4 a1 = *reinterpret_cast<const float4*>(asrc + 4);
        float4 b0 = *reinterpret_cast<const float4*>(Wo + (size_t)(k0 + bk_) * Dg + n0 + bn);
        float4 b1 = *reinterpret_cast<const float4*>(Wo + (size_t)(k0 + bk_) * Dg + n0 + bn + 4);
        As[ak+0][ar] = a0.x; As[ak+1][ar] = a0.y; As[ak+2][ar] = a0.z; As[ak+3][ar] = a0.w;
        As[ak+4][ar] = a1.x; As[ak+5][ar] = a1.y; As[ak+6][ar] = a1.z; As[ak+7][ar] = a1.w;
        *reinterpret_cast<float4*>(&Bs[bk_][bn])   = b0;
        *reinterpret_cast<float4*>(&Bs[bk_][bn+4]) = b1;
        __syncthreads();
        #pragma unroll
        for (int kk = 0; kk < 16; ++kk) {
            float av[8], bw[8];
            *reinterpret_cast<float4*>(&av[0]) = *reinterpret_cast<const float4*>(&As[kk][ty*8]);
            *reinterpret_cast<float4*>(&av[4]) = *reinterpret_cast<const float4*>(&As[kk][ty*8+4]);
            *reinterpret_cast<float4*>(&bw[0]) = *reinterpret_cast<const float4*>(&Bs[kk][tx*8]);
            *reinterpret_cast<float4*>(&bw[4]) = *reinterpret_cast<const float4*>(&Bs[kk][tx*8+4]);
            #pragma unroll
            for (int i = 0; i < 8; ++i)
                #pragma unroll
                for (int j = 0; j < 8; ++j)
                    acc[i][j] = fmaf(av[i], bw[j], acc[i][j]);
        }
        __syncthreads();
    }
    #pragma unroll
    for (int i = 0; i < 8; ++i) {
        int m = m0 + ty*8 + i;
        #pragma unroll
        for (int jq = 0; jq < 2; ++jq) {
            int c0 = n0 + tx*8 + jq*4;
            float4 v;
            v.x = acc[i][jq*4+0] + bo[c0+0];
            v.y = acc[i][jq*4+1] + bo[c0+1];
            v.z = acc[i][jq*4+2] + bo[c0+2];
            v.w = acc[i][jq*4+3] + bo[c0+3];
            *reinterpret_cast<float4*>(enc + (size_t)m * Dg + c0) = v;
        }
    }
}

// ---------------- K4: pooling scores ----------------
__global__ __launch_bounds__(256) void score_kernel(
    const float* __restrict__ enc, const float* __restrict__ pw, float* __restrict__ score)
{
    int row  = blockIdx.x * 8 + (threadIdx.x >> 5);
    int lane = threadIdx.x & 31;
    const float* r = enc + (size_t)row * Dg;
    float s = 0.f;
    for (int d = lane; d < Dg; d += 32) s = fmaf(r[d], pw[d], s);
    #pragma unroll
    for (int off = 16; off > 0; off >>= 1) s += __shfl_xor(s, off);
    if (lane == 0) score[row] = s;
}

__global__ void norm_kernel(const float* __restrict__ pw, float* __restrict__ inv_norm)
{
    int t = threadIdx.x;
    float s = 0.f;
    for (int d = t; d < Dg; d += 64) s = fmaf(pw[d], pw[d], s);
    #pragma unroll
    for (int off = 32; off > 0; off >>= 1) s += __shfl_xor(s, off);
    if (t == 0) *inv_norm = 1.0f / sqrtf(s);
}

// ---------------- K5: per-graph exact top-K via rank count ----------------
__global__ __launch_bounds__(256) void topk_kernel(
    const float* __restrict__ score, float* __restrict__ vals, int* __restrict__ idxs,
    int* __restrict__ new_id, float* __restrict__ out_batch)
{
    __shared__ float sh[Ng];
    int bgr = blockIdx.x, t = threadIdx.x;
    float mine = score[(size_t)bgr * Ng + t];
    sh[t] = mine;
    __syncthreads();
    int cnt = 0;
    for (int j = 0; j < Ng; ++j) {
        float v = sh[j];
        cnt += (v > mine || (v == mine && j < t)) ? 1 : 0;
    }
    if (cnt < Kg) {
        int pos = bgr * Kg + cnt;
        vals[pos] = mine;
        idxs[pos] = t;
        new_id[bgr * Ng + t] = pos;
        out_batch[pos] = (float)bgr;
    } else {
        new_id[bgr * Ng + t] = SENT;
    }
}

// ---------------- K6: gather + tanh scale ----------------
__global__ __launch_bounds__(256) void subx_kernel(
    const float* __restrict__ enc, const float* __restrict__ vals,
    const int* __restrict__ idxs, const float* __restrict__ inv_norm,
    float* __restrict__ out_subx)
{
    int j    = blockIdx.x * 4 + (threadIdx.x >> 6);
    int lane = threadIdx.x & 63;
    int bgr  = j >> 7;
    int src  = bgr * Ng + idxs[j];
    float scale = tanhf(vals[j] * (*inv_norm));
    float4 v = reinterpret_cast<const float4*>(enc + (size_t)src * Dg)[lane];
    v.x *= scale; v.y *= scale; v.z *= scale; v.w *= scale;
    reinterpret_cast<float4*>(out_subx + (size_t)j * Dg)[lane] = v;
}

// ---------------- edge pipeline ----------------
__global__ __launch_bounds__(256) void edge_hist(
    const int* __restrict__ ei, const int* __restrict__ new_id, int* __restrict__ counts)
{
    int e = blockIdx.x * 256 + threadIdx.x;
    int r = new_id[ei[e]];
    int c = new_id[ei[Eg + e]];
    if (r != SENT && c != SENT) atomicAdd(&counts[r], 1);
}

__global__ __launch_bounds__(256) void scan_kernel(
    const int* __restrict__ counts, int* __restrict__ offsets)
{
    __shared__ int tmp[256];
    __shared__ int carry_s;
    int t = threadIdx.x;
    if (t == 0) carry_s = 0;
    __syncthreads();
    for (int base = 0; base < SENT; base += 256) {
        int v = counts[base + t];
        tmp[t] = v;
        __syncthreads();
        for (int off = 1; off < 256; off <<= 1) {
            int add = (t >= off) ? tmp[t - off] : 0;
            __syncthreads();
            tmp[t] += add;
            __syncthreads();
        }
        int incl  = tmp[t];
        int carry = carry_s;
        offsets[base + t] = carry + incl - v;
        __syncthreads();
        if (t == 255) carry_s = carry + incl;
        __syncthreads();
    }
    if (t == 0) offsets[SENT] = carry_s;
}

__global__ __launch_bounds__(256) void edge_scatter(
    const int* __restrict__ ei, const int* __restrict__ new_id,
    const int* __restrict__ offsets, int* __restrict__ cursor, int* __restrict__ bucket)
{
    int e = blockIdx.x * 256 + threadIdx.x;
    int r = new_id[ei[e]];
    int c = new_id[ei[Eg + e]];
    if (r != SENT && c != SENT) {
        int pos = offsets[r] + atomicAdd(&cursor[r], 1);
        bucket[pos] = c;
    }
}

__global__ __launch_bounds__(256) void edge_sort_emit(
    const int* __restrict__ offsets, int* bucket, float* __restrict__ out_edges)
{
    int r = blockIdx.x * 256 + threadIdx.x;
    int s = offsets[r], e = offsets[r + 1];
    for (int i = s + 1; i < e; ++i) {
        int key = bucket[i];
        int j = i - 1;
        while (j >= s && bucket[j] > key) { bucket[j+1] = bucket[j]; --j; }
        bucket[j+1] = key;
    }
    float rf = (float)r;
    for (int i = s; i < e; ++i) {
        out_edges[i]      = rf;
        out_edges[Eg + i] = (float)bucket[i];
    }
}

__global__ __launch_bounds__(256) void edge_fill(
    const int* __restrict__ offsets, float* __restrict__ out_edges)
{
    int p = blockIdx.x * 256 + threadIdx.x;
    if (p >= offsets[SENT]) {
        out_edges[p]      = (float)SENT;
        out_edges[Eg + p] = (float)SENT;
    }
}

// ---------------- launch ----------------
extern "C" void kernel_launch(void* const* d_in, const int* in_sizes, int n_in,
                              void* d_out, int out_size, void* d_ws, size_t ws_size,
                              hipStream_t stream)
{
    const float* x    = (const float*)d_in[0];
    const float* dist = (const float*)d_in[2];
    const int*   ei   = (const int*)d_in[3];
    const float* Wq = (const float*)d_in[5];
    const float* bq = (const float*)d_in[6];
    const float* Wk = (const float*)d_in[7];
    const float* bk = (const float*)d_in[8];
    const float* Wv = (const float*)d_in[9];
    const float* bv = (const float*)d_in[10];
    const float* Wo = (const float*)d_in[11];
    const float* bo = (const float*)d_in[12];
    const float* pw = (const float*)d_in[13];

    float* out       = (float*)d_out;
    float* enc_out   = out;                     // [B*N*D]
    float* subx_out  = out + 8388608;           // [B*K*D]
    float* edge_out  = out + 12582912;          // [2*E]
    float* batch_out = out + 13631488;          // [B*K]

    float* ws     = (float*)d_ws;
    float* Q      = ws;                         // 8,388,608 (reused as attn out)
    float* Kx     = ws + 8388608;
    float* Vx     = ws + 16777216;
    float* score  = ws + 25165824;
    float* vals   = ws + 25198592;
    int*   idxs   = (int*)(ws + 25214976);
    int*   new_id = (int*)(ws + 25231360);
    int*   counts = (int*)(ws + 25264128);
    int*   offsets= (int*)(ws + 25280512);
    int*   cursor = (int*)(ws + 25296928);
    float* inv_nm = ws + 25313312;
    int*   bucket = (int*)(ws + 25313344);

    hipMemsetAsync(counts, 0, SENT * sizeof(int), stream);
    hipMemsetAsync(cursor, 0, SENT * sizeof(int), stream);

    qkv_gemm      <<<dim3(BNg/128, Dg/128, 3), 256, 0, stream>>>(x, Wq,bq, Wk,bk, Wv,bv, Q, Kx, Vx);
    attn_mfma     <<<dim3(Bg*Hg),              256, 0, stream>>>(Q, Kx, Vx, dist, Q);
    out_gemm      <<<dim3(BNg/128, Dg/128),    256, 0, stream>>>(Q, Wo, bo, enc_out);
    score_kernel  <<<dim3(BNg/8),              256, 0, stream>>>(enc_out, pw, score);
    norm_kernel   <<<dim3(1),                   64, 0, stream>>>(pw, inv_nm);
    topk_kernel   <<<dim3(Bg),                 256, 0, stream>>>(score, vals, idxs, new_id, batch_out);
    subx_kernel   <<<dim3((Bg*Kg)/4),          256, 0, stream>>>(enc_out, vals, idxs, inv_nm, subx_out);
    edge_hist     <<<dim3(Eg/256),             256, 0, stream>>>(ei, new_id, counts);
    scan_kernel   <<<dim3(1),                  256, 0, stream>>>(counts, offsets);
    edge_scatter  <<<dim3(Eg/256),             256, 0, stream>>>(ei, new_id, offsets, cursor, bucket);
    edge_sort_emit<<<dim3(SENT/256),           256, 0, stream>>>(offsets, bucket, edge_out);
    edge_fill     <<<dim3(Eg/256),             256, 0, stream>>>(offsets, edge_out);
    (void)in_sizes; (void)n_in; (void)out_size; (void)ws_size;
}

// Round 4
// 242.539 us; speedup vs baseline: 2.3417x; 1.7264x over previous
//
#include <hip/hip_runtime.h>
#include <math.h>

#define Bg   128
#define Ng   256
#define Dg   256
#define Hg   8
#define HDg  32
#define Eg   524288
#define Kg   128
#define BNg  32768
#define SENT 16384   // = Bg*Kg

using bf16x8 = __attribute__((ext_vector_type(8))) short;
using f32x4  = __attribute__((ext_vector_type(4))) float;

// split f32 -> bf16 hi (truncated) + bf16 lo (residual)
__device__ inline void split2(float x, short &h, short &l) {
    unsigned u = __float_as_uint(x);
    h = (short)(u >> 16);
    float hf = __uint_as_float(u & 0xffff0000u);
    float r = x - hf;
    l = (short)(__float_as_uint(r) >> 16);
}
__device__ inline unsigned packsplit(float x) {
    unsigned u = __float_as_uint(x);
    float hf = __uint_as_float(u & 0xffff0000u);
    float r = x - hf;
    unsigned lu = __float_as_uint(r);
    return (u >> 16) | (lu & 0xffff0000u);
}
__device__ inline unsigned pack2(short a, short b) {
    return (unsigned)(unsigned short)a | ((unsigned)(unsigned short)b << 16);
}

// ---------------- P1: split x into hi/lo bf16 ----------------
__global__ __launch_bounds__(256) void split_x(
    const float* __restrict__ x, short* __restrict__ xh, short* __restrict__ xl)
{
    size_t i = ((size_t)blockIdx.x * 256 + threadIdx.x) * 8;
    float4 a = *(const float4*)(x + i);
    float4 b = *(const float4*)(x + i + 4);
    float v[8] = {a.x,a.y,a.z,a.w,b.x,b.y,b.z,b.w};
    short h[8], l[8];
    #pragma unroll
    for (int j = 0; j < 8; ++j) split2(v[j], h[j], l[j]);
    uint4 uh, ul;
    uh.x = pack2(h[0],h[1]); uh.y = pack2(h[2],h[3]);
    uh.z = pack2(h[4],h[5]); uh.w = pack2(h[6],h[7]);
    ul.x = pack2(l[0],l[1]); ul.y = pack2(l[2],l[3]);
    ul.z = pack2(l[4],l[5]); ul.w = pack2(l[6],l[7]);
    *(uint4*)(xh + i) = uh;
    *(uint4*)(xl + i) = ul;
}

// ---------------- P2: transpose + split weights: WT[n][k] = W[k][n] ----------
__global__ __launch_bounds__(256) void wprep(
    const float* __restrict__ Wq, const float* __restrict__ Wk,
    const float* __restrict__ Wv, const float* __restrict__ Wo,
    short* __restrict__ WTh, short* __restrict__ WTl)
{
    __shared__ float t[64][65];
    const int bid = blockIdx.x;          // 0..63
    const int mat = bid >> 4;
    const int kt = (bid >> 2) & 3, nt = bid & 3;
    const float* W = (mat==0) ? Wq : (mat==1) ? Wk : (mat==2) ? Wv : Wo;
    const int tid = threadIdx.x;
    const int r = tid >> 2, c4 = tid & 3;
    #pragma unroll
    for (int i = 0; i < 4; ++i) {
        float4 v = *(const float4*)(W + (size_t)(kt*64 + r)*256 + nt*64 + c4*16 + i*4);
        t[r][c4*16 + i*4 + 0] = v.x; t[r][c4*16 + i*4 + 1] = v.y;
        t[r][c4*16 + i*4 + 2] = v.z; t[r][c4*16 + i*4 + 3] = v.w;
    }
    __syncthreads();
    const int n = r, k0 = c4 * 16;
    short hb[16], lb[16];
    #pragma unroll
    for (int i = 0; i < 16; ++i) split2(t[k0 + i][n], hb[i], lb[i]);
    size_t base = (size_t)mat*65536 + (size_t)(nt*64 + n)*256 + kt*64 + k0;
    uint4 uh0, uh1, ul0, ul1;
    uh0.x=pack2(hb[0],hb[1]);  uh0.y=pack2(hb[2],hb[3]);  uh0.z=pack2(hb[4],hb[5]);  uh0.w=pack2(hb[6],hb[7]);
    uh1.x=pack2(hb[8],hb[9]);  uh1.y=pack2(hb[10],hb[11]);uh1.z=pack2(hb[12],hb[13]);uh1.w=pack2(hb[14],hb[15]);
    ul0.x=pack2(lb[0],lb[1]);  ul0.y=pack2(lb[2],lb[3]);  ul0.z=pack2(lb[4],lb[5]);  ul0.w=pack2(lb[6],lb[7]);
    ul1.x=pack2(lb[8],lb[9]);  ul1.y=pack2(lb[10],lb[11]);ul1.z=pack2(lb[12],lb[13]);ul1.w=pack2(lb[14],lb[15]);
    *(uint4*)&WTh[base]     = uh0; *(uint4*)&WTh[base + 8] = uh1;
    *(uint4*)&WTl[base]     = ul0; *(uint4*)&WTl[base + 8] = ul1;
}

// ---------------- K1: QKV projection via 4-term split MFMA -------------------
// A = xh/xl [BN][256] bf16; B = WT[n][k] hi/lo; out f32 [b,h,n,hd] (+bias)
__global__ __launch_bounds__(256) void qkv_mm(
    const short* __restrict__ xh, const short* __restrict__ xl,
    const short* __restrict__ WTh, const short* __restrict__ WTl,
    const float* __restrict__ bq, const float* __restrict__ bk, const float* __restrict__ bv,
    float* __restrict__ Qo, float* __restrict__ Ko, float* __restrict__ Vo)
{
    const int z = blockIdx.z;
    const float* bias = (z==0) ? bq : (z==1) ? bk : bv;
    float* out        = (z==0) ? Qo : (z==1) ? Ko : Vo;
    const short* bth = WTh + (size_t)z * 65536;
    const short* btl = WTl + (size_t)z * 65536;
    __shared__ __align__(16) short lds[16384];   // Ah 0 | Al 4096 | Bh 8192 | Bl 12288
    const int tid = threadIdx.x;
    const int lane = tid & 63, w = tid >> 6;
    const int g = lane >> 4, li = lane & 15;
    const int wr = w >> 1, wc = w & 1;
    const int m0 = blockIdx.x * 128, n0 = blockIdx.y * 128;
    f32x4 acc[4][4];
    #pragma unroll
    for (int i = 0; i < 4; ++i)
        #pragma unroll
        for (int j = 0; j < 4; ++j) acc[i][j] = (f32x4){0.f,0.f,0.f,0.f};

    for (int k0 = 0; k0 < 256; k0 += 32) {
        #pragma unroll
        for (int it = 0; it < 2; ++it) {
            int chunk = it*256 + tid;
            int r = chunk >> 2, c = chunk & 3;
            size_t ga = (size_t)(m0 + r)*256 + k0 + c*8;
            size_t gb = (size_t)(n0 + r)*256 + k0 + c*8;
            uint4 vh = *(const uint4*)(xh + ga);
            uint4 vl = *(const uint4*)(xl + ga);
            uint4 wh = *(const uint4*)(bth + gb);
            uint4 wl = *(const uint4*)(btl + gb);
            *(uint4*)&lds[        chunk*8] = vh;
            *(uint4*)&lds[ 4096 + chunk*8] = vl;
            *(uint4*)&lds[ 8192 + chunk*8] = wh;
            *(uint4*)&lds[12288 + chunk*8] = wl;
        }
        __syncthreads();
        bf16x8 ah[4], al[4], bh[4], bl[4];
        #pragma unroll
        for (int i = 0; i < 4; ++i) {
            int row = wr*64 + i*16 + li;
            ah[i] = *(const bf16x8*)&lds[       row*32 + g*8];
            al[i] = *(const bf16x8*)&lds[4096 + row*32 + g*8];
        }
        #pragma unroll
        for (int j = 0; j < 4; ++j) {
            int row = wc*64 + j*16 + li;
            bh[j] = *(const bf16x8*)&lds[ 8192 + row*32 + g*8];
            bl[j] = *(const bf16x8*)&lds[12288 + row*32 + g*8];
        }
        #pragma unroll
        for (int i = 0; i < 4; ++i)
            #pragma unroll
            for (int j = 0; j < 4; ++j) {
                acc[i][j] = __builtin_amdgcn_mfma_f32_16x16x32_bf16(ah[i], bh[j], acc[i][j], 0,0,0);
                acc[i][j] = __builtin_amdgcn_mfma_f32_16x16x32_bf16(ah[i], bl[j], acc[i][j], 0,0,0);
                acc[i][j] = __builtin_amdgcn_mfma_f32_16x16x32_bf16(al[i], bh[j], acc[i][j], 0,0,0);
                acc[i][j] = __builtin_amdgcn_mfma_f32_16x16x32_bf16(al[i], bl[j], acc[i][j], 0,0,0);
            }
        __syncthreads();
    }
    #pragma unroll
    for (int i = 0; i < 4; ++i)
        #pragma unroll
        for (int j = 0; j < 4; ++j)
            #pragma unroll
            for (int r = 0; r < 4; ++r) {
                int m = m0 + wr*64 + i*16 + g*4 + r;
                int c = n0 + wc*64 + j*16 + li;
                int b = m >> 8, nn = m & 255;
                int h = c >> 5, hd = c & 31;
                out[((size_t)(b*Hg + h)*Ng + nn)*HDg + hd] = acc[i][j][r] + bias[c];
            }
}

// ---------------- K2: MFMA flash attention (4-term splits) -------------------
// Writes AO as split-bf16 (AOh/AOl) in [node_row][h*32+hd] layout for out_mm.
__global__ __launch_bounds__(256) void attn_mfma(
    const float* Qf, const float* __restrict__ Kx,
    const float* __restrict__ Vx, const float* __restrict__ dist,
    short* __restrict__ AOh, short* __restrict__ AOl)
{
    __shared__ short    Khi[2][32][40];
    __shared__ short    Klo[2][32][40];
    __shared__ unsigned Vt [2][32][36];
    __shared__ unsigned P32[4][64][36];

    const int bh = blockIdx.x;
    const int b  = bh >> 3;
    const int h  = bh & 7;
    const int tid = threadIdx.x;
    const int w = tid >> 6;
    const int lane = tid & 63;
    const int g = lane >> 4;
    const int li = lane & 15;
    const int q0 = w * 64;

    bf16x8 qh[4], ql[4];
    #pragma unroll
    for (int tq = 0; tq < 4; ++tq) {
        const float* qp = Qf + ((size_t)bh * Ng + q0 + tq*16 + li) * HDg + g*8;
        float4 qa = *(const float4*)qp;
        float4 qb = *(const float4*)(qp + 4);
        float v[8] = {qa.x,qa.y,qa.z,qa.w,qb.x,qb.y,qb.z,qb.w};
        #pragma unroll
        for (int j = 0; j < 8; ++j) {
            short hh,ll; split2(v[j] * 0.17677669529663687f, hh, ll);
            qh[tq][j] = hh; ql[tq][j] = ll;
        }
    }

    {
        int key = tid >> 3, e0 = (tid & 7) * 4;
        float4 kv = *(const float4*)(Kx + ((size_t)bh*Ng + key) * HDg + e0);
        float4 vv = *(const float4*)(Vx + ((size_t)bh*Ng + key) * HDg + e0);
        float ka[4] = {kv.x,kv.y,kv.z,kv.w}, va[4] = {vv.x,vv.y,vv.z,vv.w};
        #pragma unroll
        for (int i = 0; i < 4; ++i) {
            short hh,ll; split2(ka[i], hh, ll);
            Khi[0][key][e0+i] = hh; Klo[0][key][e0+i] = ll;
            Vt[0][e0+i][key] = packsplit(va[i]);
        }
    }
    __syncthreads();

    f32x4 O[4][2];
    #pragma unroll
    for (int tq=0;tq<4;++tq)
        #pragma unroll
        for (int td=0;td<2;++td) O[tq][td] = (f32x4){0.f,0.f,0.f,0.f};
    float lpart[4][4] = {};

    for (int ch = 0; ch < 8; ++ch) {
        const int cur = ch & 1;
        if (ch < 7) {
            int key = tid >> 3, e0 = (tid & 7) * 4;
            float4 kv = *(const float4*)(Kx + ((size_t)bh*Ng + (ch+1)*32 + key) * HDg + e0);
            float4 vv = *(const float4*)(Vx + ((size_t)bh*Ng + (ch+1)*32 + key) * HDg + e0);
            float ka[4]={kv.x,kv.y,kv.z,kv.w}, va[4]={vv.x,vv.y,vv.z,vv.w};
            int nb = cur ^ 1;
            #pragma unroll
            for (int i = 0; i < 4; ++i) {
                short hh,ll; split2(ka[i], hh, ll);
                Khi[nb][key][e0+i] = hh; Klo[nb][key][e0+i] = ll;
                Vt[nb][e0+i][key] = packsplit(va[i]);
            }
        }
        f32x4 sacc[4][2];
        const float* dbase = dist + (size_t)b*Ng*Ng + ch*32;
        #pragma unroll
        for (int tq = 0; tq < 4; ++tq)
            #pragma unroll
            for (int tc = 0; tc < 2; ++tc) {
                const float* dp = dbase + (size_t)(q0 + tq*16 + g*4)*Ng + tc*16 + li;
                f32x4 s;
                s[0]=dp[0]; s[1]=dp[Ng]; s[2]=dp[2*Ng]; s[3]=dp[3*Ng];
                sacc[tq][tc] = s;
            }
        bf16x8 kbh[2], kbl[2];
        #pragma unroll
        for (int tc = 0; tc < 2; ++tc) {
            kbh[tc] = *(const bf16x8*)&Khi[cur][tc*16+li][g*8];
            kbl[tc] = *(const bf16x8*)&Klo[cur][tc*16+li][g*8];
        }
        #pragma unroll
        for (int tq = 0; tq < 4; ++tq)
            #pragma unroll
            for (int tc = 0; tc < 2; ++tc) {
                sacc[tq][tc] = __builtin_amdgcn_mfma_f32_16x16x32_bf16(qh[tq], kbh[tc], sacc[tq][tc], 0,0,0);
                sacc[tq][tc] = __builtin_amdgcn_mfma_f32_16x16x32_bf16(qh[tq], kbl[tc], sacc[tq][tc], 0,0,0);
                sacc[tq][tc] = __builtin_amdgcn_mfma_f32_16x16x32_bf16(ql[tq], kbh[tc], sacc[tq][tc], 0,0,0);
                sacc[tq][tc] = __builtin_amdgcn_mfma_f32_16x16x32_bf16(ql[tq], kbl[tc], sacc[tq][tc], 0,0,0);
            }
        #pragma unroll
        for (int tq = 0; tq < 4; ++tq)
            #pragma unroll
            for (int tc = 0; tc < 2; ++tc)
                #pragma unroll
                for (int r = 0; r < 4; ++r) {
                    float p = __expf(sacc[tq][tc][r] - 16.f);
                    lpart[tq][r] += p;
                    P32[w][tq*16 + g*4 + r][tc*16 + li] = packsplit(p);
                }
        __syncthreads();
        bf16x8 vbh[2], vbl[2];
        #pragma unroll
        for (int td = 0; td < 2; ++td) {
            unsigned tmp[8];
            *(uint4*)&tmp[0] = *(const uint4*)&Vt[cur][td*16+li][g*8];
            *(uint4*)&tmp[4] = *(const uint4*)&Vt[cur][td*16+li][g*8+4];
            #pragma unroll
            for (int j=0;j<8;++j){ vbh[td][j]=(short)(tmp[j]&0xffff); vbl[td][j]=(short)(tmp[j]>>16); }
        }
        #pragma unroll
        for (int tq = 0; tq < 4; ++tq) {
            unsigned tmp[8];
            *(uint4*)&tmp[0] = *(const uint4*)&P32[w][tq*16+li][g*8];
            *(uint4*)&tmp[4] = *(const uint4*)&P32[w][tq*16+li][g*8+4];
            bf16x8 ph, pl;
            #pragma unroll
            for (int j=0;j<8;++j){ ph[j]=(short)(tmp[j]&0xffff); pl[j]=(short)(tmp[j]>>16); }
            #pragma unroll
            for (int td = 0; td < 2; ++td) {
                O[tq][td] = __builtin_amdgcn_mfma_f32_16x16x32_bf16(ph, vbh[td], O[tq][td], 0,0,0);
                O[tq][td] = __builtin_amdgcn_mfma_f32_16x16x32_bf16(ph, vbl[td], O[tq][td], 0,0,0);
                O[tq][td] = __builtin_amdgcn_mfma_f32_16x16x32_bf16(pl, vbh[td], O[tq][td], 0,0,0);
                O[tq][td] = __builtin_amdgcn_mfma_f32_16x16x32_bf16(pl, vbl[td], O[tq][td], 0,0,0);
            }
        }
        __syncthreads();
    }
    #pragma unroll
    for (int tq = 0; tq < 4; ++tq)
        #pragma unroll
        for (int r = 0; r < 4; ++r) {
            float s = lpart[tq][r];
            s += __shfl_xor(s, 1); s += __shfl_xor(s, 2);
            s += __shfl_xor(s, 4); s += __shfl_xor(s, 8);
            lpart[tq][r] = 1.f / s;
        }
    #pragma unroll
    for (int tq = 0; tq < 4; ++tq)
        #pragma unroll
        for (int td = 0; td < 2; ++td)
            #pragma unroll
            for (int r = 0; r < 4; ++r) {
                int q = q0 + tq*16 + g*4 + r;
                float val = O[tq][td][r] * lpart[tq][r];
                short hh, ll; split2(val, hh, ll);
                size_t idx = ((size_t)b*Ng + q)*Dg + h*HDg + td*16 + li;
                AOh[idx] = hh; AOl[idx] = ll;
            }
}

// ---------------- K3: output projection via 4-term split MFMA ----------------
__global__ __launch_bounds__(256) void out_mm(
    const short* __restrict__ ah_g, const short* __restrict__ al_g,
    const short* __restrict__ bth, const short* __restrict__ btl,
    const float* __restrict__ bo, float* __restrict__ enc)
{
    __shared__ __align__(16) short lds[16384];
    const int tid = threadIdx.x;
    const int lane = tid & 63, w = tid >> 6;
    const int g = lane >> 4, li = lane & 15;
    const int wr = w >> 1, wc = w & 1;
    const int m0 = blockIdx.x * 128, n0 = blockIdx.y * 128;
    f32x4 acc[4][4];
    #pragma unroll
    for (int i = 0; i < 4; ++i)
        #pragma unroll
        for (int j = 0; j < 4; ++j) acc[i][j] = (f32x4){0.f,0.f,0.f,0.f};

    for (int k0 = 0; k0 < 256; k0 += 32) {
        #pragma unroll
        for (int it = 0; it < 2; ++it) {
            int chunk = it*256 + tid;
            int r = chunk >> 2, c = chunk & 3;
            size_t ga = (size_t)(m0 + r)*256 + k0 + c*8;
            size_t gb = (size_t)(n0 + r)*256 + k0 + c*8;
            uint4 vh = *(const uint4*)(ah_g + ga);
            uint4 vl = *(const uint4*)(al_g + ga);
            uint4 wh = *(const uint4*)(bth + gb);
            uint4 wl = *(const uint4*)(btl + gb);
            *(uint4*)&lds[        chunk*8] = vh;
            *(uint4*)&lds[ 4096 + chunk*8] = vl;
            *(uint4*)&lds[ 8192 + chunk*8] = wh;
            *(uint4*)&lds[12288 + chunk*8] = wl;
        }
        __syncthreads();
        bf16x8 ah[4], al[4], bh[4], bl[4];
        #pragma unroll
        for (int i = 0; i < 4; ++i) {
            int row = wr*64 + i*16 + li;
            ah[i] = *(const bf16x8*)&lds[       row*32 + g*8];
            al[i] = *(const bf16x8*)&lds[4096 + row*32 + g*8];
        }
        #pragma unroll
        for (int j = 0; j < 4; ++j) {
            int row = wc*64 + j*16 + li;
            bh[j] = *(const bf16x8*)&lds[ 8192 + row*32 + g*8];
            bl[j] = *(const bf16x8*)&lds[12288 + row*32 + g*8];
        }
        #pragma unroll
        for (int i = 0; i < 4; ++i)
            #pragma unroll
            for (int j = 0; j < 4; ++j) {
                acc[i][j] = __builtin_amdgcn_mfma_f32_16x16x32_bf16(ah[i], bh[j], acc[i][j], 0,0,0);
                acc[i][j] = __builtin_amdgcn_mfma_f32_16x16x32_bf16(ah[i], bl[j], acc[i][j], 0,0,0);
                acc[i][j] = __builtin_amdgcn_mfma_f32_16x16x32_bf16(al[i], bh[j], acc[i][j], 0,0,0);
                acc[i][j] = __builtin_amdgcn_mfma_f32_16x16x32_bf16(al[i], bl[j], acc[i][j], 0,0,0);
            }
        __syncthreads();
    }
    #pragma unroll
    for (int i = 0; i < 4; ++i)
        #pragma unroll
        for (int j = 0; j < 4; ++j)
            #pragma unroll
            for (int r = 0; r < 4; ++r) {
                int m = m0 + wr*64 + i*16 + g*4 + r;
                int c = n0 + wc*64 + j*16 + li;
                enc[(size_t)m*Dg + c] = acc[i][j][r] + bo[c];
            }
}

// ---------------- K4: pooling scores ----------------
__global__ __launch_bounds__(256) void score_kernel(
    const float* __restrict__ enc, const float* __restrict__ pw, float* __restrict__ score)
{
    int row  = blockIdx.x * 8 + (threadIdx.x >> 5);
    int lane = threadIdx.x & 31;
    const float* r = enc + (size_t)row * Dg;
    float s = 0.f;
    for (int d = lane; d < Dg; d += 32) s = fmaf(r[d], pw[d], s);
    #pragma unroll
    for (int off = 16; off > 0; off >>= 1) s += __shfl_xor(s, off);
    if (lane == 0) score[row] = s;
}

__global__ void norm_kernel(const float* __restrict__ pw, float* __restrict__ inv_norm)
{
    int t = threadIdx.x;
    float s = 0.f;
    for (int d = t; d < Dg; d += 64) s = fmaf(pw[d], pw[d], s);
    #pragma unroll
    for (int off = 32; off > 0; off >>= 1) s += __shfl_xor(s, off);
    if (t == 0) *inv_norm = 1.0f / sqrtf(s);
}

// ---------------- K5: per-graph exact top-K via rank count ----------------
__global__ __launch_bounds__(256) void topk_kernel(
    const float* __restrict__ score, float* __restrict__ vals, int* __restrict__ idxs,
    int* __restrict__ new_id, float* __restrict__ out_batch)
{
    __shared__ float sh[Ng];
    int bgr = blockIdx.x, t = threadIdx.x;
    float mine = score[(size_t)bgr * Ng + t];
    sh[t] = mine;
    __syncthreads();
    int cnt = 0;
    for (int j = 0; j < Ng; ++j) {
        float v = sh[j];
        cnt += (v > mine || (v == mine && j < t)) ? 1 : 0;
    }
    if (cnt < Kg) {
        int pos = bgr * Kg + cnt;
        vals[pos] = mine;
        idxs[pos] = t;
        new_id[bgr * Ng + t] = pos;
        out_batch[pos] = (float)bgr;
    } else {
        new_id[bgr * Ng + t] = SENT;
    }
}

// ---------------- K6: gather + tanh scale ----------------
__global__ __launch_bounds__(256) void subx_kernel(
    const float* __restrict__ enc, const float* __restrict__ vals,
    const int* __restrict__ idxs, const float* __restrict__ inv_norm,
    float* __restrict__ out_subx)
{
    int j    = blockIdx.x * 4 + (threadIdx.x >> 6);
    int lane = threadIdx.x & 63;
    int bgr  = j >> 7;
    int src  = bgr * Ng + idxs[j];
    float scale = tanhf(vals[j] * (*inv_norm));
    float4 v = reinterpret_cast<const float4*>(enc + (size_t)src * Dg)[lane];
    v.x *= scale; v.y *= scale; v.z *= scale; v.w *= scale;
    reinterpret_cast<float4*>(out_subx + (size_t)j * Dg)[lane] = v;
}

// ---------------- edge pipeline ----------------
__global__ __launch_bounds__(256) void edge_hist(
    const int* __restrict__ ei, const int* __restrict__ new_id, int* __restrict__ counts)
{
    int e = blockIdx.x * 256 + threadIdx.x;
    int r = new_id[ei[e]];
    int c = new_id[ei[Eg + e]];
    if (r != SENT && c != SENT) atomicAdd(&counts[r], 1);
}

// two-level scan: 256 threads x 64 elems each
__global__ __launch_bounds__(256) void scan_kernel(
    const int* __restrict__ counts, int* __restrict__ offsets)
{
    __shared__ int sums[256];
    int t = threadIdx.x;
    int base = t * 64;
    int s = 0;
    for (int i = 0; i < 64; ++i) s += counts[base + i];
    sums[t] = s;
    __syncthreads();
    for (int off = 1; off < 256; off <<= 1) {
        int add = (t >= off) ? sums[t - off] : 0;
        __syncthreads();
        sums[t] += add;
        __syncthreads();
    }
    int run = sums[t] - s;     // exclusive prefix of this segment
    for (int i = 0; i < 64; ++i) { offsets[base + i] = run; run += counts[base + i]; }
    if (t == 255) offsets[SENT] = run;
}

__global__ __launch_bounds__(256) void edge_scatter(
    const int* __restrict__ ei, const int* __restrict__ new_id,
    const int* __restrict__ offsets, int* __restrict__ cursor, int* __restrict__ bucket)
{
    int e = blockIdx.x * 256 + threadIdx.x;
    int r = new_id[ei[e]];
    int c = new_id[ei[Eg + e]];
    if (r != SENT && c != SENT) {
        int pos = offsets[r] + atomicAdd(&cursor[r], 1);
        bucket[pos] = c;
    }
}

__global__ __launch_bounds__(256) void edge_sort_emit(
    const int* __restrict__ offsets, int* bucket, float* __restrict__ out_edges)
{
    int r = blockIdx.x * 256 + threadIdx.x;
    int s = offsets[r], e = offsets[r + 1];
    for (int i = s + 1; i < e; ++i) {
        int key = bucket[i];
        int j = i - 1;
        while (j >= s && bucket[j] > key) { bucket[j+1] = bucket[j]; --j; }
        bucket[j+1] = key;
    }
    float rf = (float)r;
    for (int i = s; i < e; ++i) {
        out_edges[i]      = rf;
        out_edges[Eg + i] = (float)bucket[i];
    }
}

__global__ __launch_bounds__(256) void edge_fill(
    const int* __restrict__ offsets, float* __restrict__ out_edges)
{
    int p = blockIdx.x * 256 + threadIdx.x;
    if (p >= offsets[SENT]) {
        out_edges[p]      = (float)SENT;
        out_edges[Eg + p] = (float)SENT;
    }
}

// ---------------- launch ----------------
extern "C" void kernel_launch(void* const* d_in, const int* in_sizes, int n_in,
                              void* d_out, int out_size, void* d_ws, size_t ws_size,
                              hipStream_t stream)
{
    const float* x    = (const float*)d_in[0];
    const float* dist = (const float*)d_in[2];
    const int*   ei   = (const int*)d_in[3];
    const float* Wq = (const float*)d_in[5];
    const float* bq = (const float*)d_in[6];
    const float* Wk = (const float*)d_in[7];
    const float* bk = (const float*)d_in[8];
    const float* Wv = (const float*)d_in[9];
    const float* bv = (const float*)d_in[10];
    const float* Wo = (const float*)d_in[11];
    const float* bo = (const float*)d_in[12];
    const float* pw = (const float*)d_in[13];

    float* out       = (float*)d_out;
    float* enc_out   = out;                     // [B*N*D]
    float* subx_out  = out + 8388608;           // [B*K*D]
    float* edge_out  = out + 12582912;          // [2*E]
    float* batch_out = out + 13631488;          // [B*K]

    float* ws     = (float*)d_ws;
    float* Q      = ws;                         // 8,388,608
    float* Kx     = ws + 8388608;               // 8,388,608
    float* Vx     = ws + 16777216;              // 8,388,608
    short* xh     = (short*)(ws + 25165824);    // 8,388,608 bf16 (aliased: AOh)
    short* xl     = (short*)(ws + 29360128);    // 8,388,608 bf16 (aliased: AOl)
    short* AOh    = xh;
    short* AOl    = xl;
    short* WTh    = (short*)(ws + 33554432);    // 4*65536 bf16
    short* WTl    = (short*)(ws + 33685504);
    float* score  = ws + 33816576;              // 32768
    float* vals   = ws + 33849344;              // 16384
    int*   idxs   = (int*)(ws + 33865728);      // 16384
    int*   new_id = (int*)(ws + 33882112);      // 32768
    int*   counts = (int*)(ws + 33914880);      // 16384
    int*   offsets= (int*)(ws + 33931264);      // 16416
    int*   cursor = (int*)(ws + 33947680);      // 16384
    float* inv_nm = ws + 33964064;              // 32
    int*   bucket = (int*)(ws + 33964096);      // 524288
    // total 34,488,384 floats ~= 138 MB

    hipMemsetAsync(counts, 0, SENT * sizeof(int), stream);
    hipMemsetAsync(cursor, 0, SENT * sizeof(int), stream);

    split_x       <<<dim3(4096),               256, 0, stream>>>(x, xh, xl);
    wprep         <<<dim3(64),                 256, 0, stream>>>(Wq, Wk, Wv, Wo, WTh, WTl);
    norm_kernel   <<<dim3(1),                   64, 0, stream>>>(pw, inv_nm);
    qkv_mm        <<<dim3(BNg/128, Dg/128, 3), 256, 0, stream>>>(xh, xl, WTh, WTl, bq, bk, bv, Q, Kx, Vx);
    attn_mfma     <<<dim3(Bg*Hg),              256, 0, stream>>>(Q, Kx, Vx, dist, AOh, AOl);
    out_mm        <<<dim3(BNg/128, Dg/128),    256, 0, stream>>>(AOh, AOl, WTh + 3*65536, WTl + 3*65536, bo, enc_out);
    score_kernel  <<<dim3(BNg/8),              256, 0, stream>>>(enc_out, pw, score);
    topk_kernel   <<<dim3(Bg),                 256, 0, stream>>>(score, vals, idxs, new_id, batch_out);
    subx_kernel   <<<dim3((Bg*Kg)/4),          256, 0, stream>>>(enc_out, vals, idxs, inv_nm, subx_out);
    edge_hist     <<<dim3(Eg/256),             256, 0, stream>>>(ei, new_id, counts);
    scan_kernel   <<<dim3(1),                  256, 0, stream>>>(counts, offsets);
    edge_scatter  <<<dim3(Eg/256),             256, 0, stream>>>(ei, new_id, offsets, cursor, bucket);
    edge_sort_emit<<<dim3(SENT/256),           256, 0, stream>>>(offsets, bucket, edge_out);
    edge_fill     <<<dim3(Eg/256),             256, 0, stream>>>(offsets, edge_out);
    (void)in_sizes; (void)n_in; (void)out_size; (void)ws_size;
}